// Round 1
// baseline (1015.991 us; speedup 1.0000x reference)
//
#include <hip/hip_runtime.h>
#include <stdint.h>

#define TOKENS 8192
#define KIN    4096
#define NOUT   11008

#define BM 128
#define BN 128
#define BK 32
#define KSTEPS (KIN / BK)   // 128
#define NTROW (TOKENS / BM) // 64
#define NTCOL (NOUT / BN)   // 86

using bf16x8 = __attribute__((ext_vector_type(8))) short;
using f32x4  = __attribute__((ext_vector_type(4))) float;

static __device__ __forceinline__ unsigned short f32_to_bf16(float f) {
  union { float f; uint32_t u; } v; v.f = f;
  uint32_t u = v.u;
  u += 0x7fffu + ((u >> 16) & 1u);   // round-to-nearest-even
  return (unsigned short)(u >> 16);
}

static __device__ __forceinline__ void gload_lds16(const void* g, void* l) {
  __builtin_amdgcn_global_load_lds((const __attribute__((address_space(1))) void*)g,
                                   (__attribute__((address_space(3))) void*)l,
                                   16, 0, 0);
}

// ---- kernel 1: per-row absmean quantization: Wq = bf16(round(W/scale)), scale[row] ----
__global__ __launch_bounds__(256) void quant_weight_k(const float* __restrict__ W,
                                                      unsigned short* __restrict__ Wq,
                                                      float* __restrict__ scale) {
  const int row = blockIdx.x;
  const int t   = threadIdx.x;
  const float4* wr = reinterpret_cast<const float4*>(W + (size_t)row * KIN);
  float4 v[4];
  double s = 0.0;
#pragma unroll
  for (int i = 0; i < 4; ++i) {
    v[i] = wr[t + i * 256];
    s += fabs((double)v[i].x) + fabs((double)v[i].y) +
         fabs((double)v[i].z) + fabs((double)v[i].w);
  }
#pragma unroll
  for (int off = 32; off > 0; off >>= 1) s += __shfl_down(s, off);
  __shared__ double red[4];
  if ((t & 63) == 0) red[t >> 6] = s;
  __syncthreads();
  const float sc = (float)((red[0] + red[1] + red[2] + red[3]) * (1.0 / KIN));
  if (t == 0) scale[row] = sc;
  ushort4* qr = reinterpret_cast<ushort4*>(Wq + (size_t)row * KIN);
#pragma unroll
  for (int i = 0; i < 4; ++i) {
    ushort4 q;
    q.x = f32_to_bf16(rintf(v[i].x / sc));
    q.y = f32_to_bf16(rintf(v[i].y / sc));
    q.z = f32_to_bf16(rintf(v[i].z / sc));
    q.w = f32_to_bf16(rintf(v[i].w / sc));
    qr[t + i * 256] = q;
  }
}

// ---- kernel 2: input fp32 -> bf16 ----
__global__ __launch_bounds__(256) void conv_input_k(const float* __restrict__ X,
                                                    unsigned short* __restrict__ Xb) {
  const int i = blockIdx.x * 256 + threadIdx.x;
  float4 v = reinterpret_cast<const float4*>(X)[i];
  ushort4 q;
  q.x = f32_to_bf16(v.x); q.y = f32_to_bf16(v.y);
  q.z = f32_to_bf16(v.z); q.w = f32_to_bf16(v.w);
  reinterpret_cast<ushort4*>(Xb)[i] = q;
}

// ---- kernel 3: C[t,o] = scale[o] * (Xb[t,:] . Wq[o,:]) + bias[o] ----
// 128x128 tile, BK=32, 4 waves (2x2), 16x16x32 bf16 MFMA, global_load_lds staging.
__global__ __launch_bounds__(256) void gemm_k(const unsigned short* __restrict__ Xb,
                                              const unsigned short* __restrict__ Wq,
                                              const float* __restrict__ scale,
                                              const float* __restrict__ bias,
                                              float* __restrict__ out) {
  __shared__ unsigned short As[BM * BK];   // 8 KB, [128][32] bf16, linear
  __shared__ unsigned short Bs[BN * BK];   // 8 KB

  // XCD-aware swizzle: nwg = 5504, divisible by 8 -> simple form is bijective
  int bid = (int)blockIdx.x;
  const int cpx = (NTROW * NTCOL) >> 3;    // 688
  bid = (bid & 7) * cpx + (bid >> 3);
  const int trow = bid / NTCOL;
  const int tcol = bid - trow * NTCOL;

  const int tid  = (int)threadIdx.x;
  const int lane = tid & 63;
  const int wave = tid >> 6;
  const int wm = wave >> 1, wn = wave & 1;

  // staging geometry: chunk c (0/1) covers rows c*64..c*64+63 of the tile;
  // wave w covers rows w*16..w*16+15 of the chunk; lane l -> row +(l>>2), bytes (l&3)*16.
  // LDS dest is wave-uniform base + lane*16 (linear), which matches row*64+(l&3)*16.
  const int r0 = wave * 16 + (lane >> 2);
  const int kb = (lane & 3) * 16;
  const size_t rowbytes = (size_t)KIN * 2;  // 8192

  const char* gA = (const char*)(Xb + (size_t)trow * BM * KIN);
  const char* gB = (const char*)(Wq + (size_t)tcol * BN * KIN);
  const char* pA0 = gA + (size_t)r0 * rowbytes + kb;
  const char* pB0 = gB + (size_t)r0 * rowbytes + kb;
  char* lA = (char*)As + wave * 1024;
  char* lB = (char*)Bs + wave * 1024;

  f32x4 acc[4][4];
#pragma unroll
  for (int m = 0; m < 4; ++m)
#pragma unroll
    for (int n = 0; n < 4; ++n) acc[m][n] = (f32x4){0.f, 0.f, 0.f, 0.f};

  const int lr = lane & 15;
  const int hi = lane >> 4;

  for (int kt = 0; kt < KSTEPS; ++kt) {
    const int koff = kt * 64;  // 32 bf16 = 64 bytes per K-step
    gload_lds16(pA0 + koff, lA);
    gload_lds16(pA0 + (size_t)64 * rowbytes + koff, lA + 4096);
    gload_lds16(pB0 + koff, lB);
    gload_lds16(pB0 + (size_t)64 * rowbytes + koff, lB + 4096);
    __syncthreads();   // compiler drains vmcnt before s_barrier

    bf16x8 a[4], b[4];
#pragma unroll
    for (int m = 0; m < 4; ++m)
      a[m] = *reinterpret_cast<const bf16x8*>(
          (const char*)As + (wm * 64 + m * 16 + lr) * (BK * 2) + hi * 16);
#pragma unroll
    for (int n = 0; n < 4; ++n)
      b[n] = *reinterpret_cast<const bf16x8*>(
          (const char*)Bs + (wn * 64 + n * 16 + lr) * (BK * 2) + hi * 16);
#pragma unroll
    for (int m = 0; m < 4; ++m)
#pragma unroll
      for (int n = 0; n < 4; ++n)
        acc[m][n] = __builtin_amdgcn_mfma_f32_16x16x32_bf16(a[m], b[n], acc[m][n], 0, 0, 0);
    __syncthreads();   // all waves done reading before next stage overwrites
  }

  // epilogue: C/D layout col = lane&15, row = (lane>>4)*4 + reg  [m89/m91]
  const int gr0 = trow * BM + wm * 64 + hi * 4;
  const int gc0 = tcol * BN + wn * 64 + lr;
#pragma unroll
  for (int n = 0; n < 4; ++n) {
    const int gc = gc0 + n * 16;
    const float s  = scale[gc];
    const float bb = bias[gc];
#pragma unroll
    for (int m = 0; m < 4; ++m) {
      const size_t rb = (size_t)(gr0 + m * 16) * NOUT + gc;
#pragma unroll
      for (int j = 0; j < 4; ++j)
        out[rb + (size_t)j * NOUT] = acc[m][n][j] * s + bb;
    }
  }
}

extern "C" void kernel_launch(void* const* d_in, const int* in_sizes, int n_in,
                              void* d_out, int out_size, void* d_ws, size_t ws_size,
                              hipStream_t stream) {
  const float* X  = (const float*)d_in[0];   // [8192, 4096] fp32
  const float* W  = (const float*)d_in[1];   // [11008, 4096] fp32
  const float* Bi = (const float*)d_in[2];   // [11008] fp32
  float* out = (float*)d_out;                // [8192, 11008] fp32

  const size_t xb_bytes = (size_t)TOKENS * KIN * 2;  // 64 MiB
  const size_t wq_bytes = (size_t)NOUT * KIN * 2;    // 86 MiB
  const size_t need = xb_bytes + wq_bytes + (size_t)NOUT * sizeof(float);
  if (ws_size < need) return;  // needs ~157.3 MB scratch

  char* ws = (char*)d_ws;
  unsigned short* Xb = (unsigned short*)ws;
  unsigned short* Wq = (unsigned short*)(ws + xb_bytes);
  float* scale = (float*)(ws + xb_bytes + wq_bytes);

  quant_weight_k<<<NOUT, 256, 0, stream>>>(W, Wq, scale);
  conv_input_k<<<(TOKENS * KIN / 4) / 256, 256, 0, stream>>>(X, Xb);
  gemm_k<<<NTROW * NTCOL, 256, 0, stream>>>(Xb, Wq, scale, Bi, out);
}

// Round 2
// 745.268 us; speedup vs baseline: 1.3633x; 1.3633x over previous
//
#include <hip/hip_runtime.h>
#include <stdint.h>

#define TOKENS 8192
#define KIN    4096
#define NOUT   11008

// ---- 256x256 8-phase GEMM geometry ----
#define BM 256
#define BN 256
#define BK 64
#define NT    (KIN / BK)      // 64 K-tiles
#define NTROW (TOKENS / BM)   // 32
#define NTCOL (NOUT / BN)     // 43
#define NWG   (NTROW * NTCOL) // 1376 (divisible by 8 -> simple XCD swizzle bijective)

using bf16x8 = __attribute__((ext_vector_type(8))) short;
using f32x4  = __attribute__((ext_vector_type(4))) float;

static __device__ __forceinline__ unsigned short f32_to_bf16(float f) {
  union { float f; uint32_t u; } v; v.f = f;
  uint32_t u = v.u;
  u += 0x7fffu + ((u >> 16) & 1u);   // round-to-nearest-even
  return (unsigned short)(u >> 16);
}

static __device__ __forceinline__ void gload_lds16(const void* g, void* l) {
  __builtin_amdgcn_global_load_lds((const __attribute__((address_space(1))) void*)g,
                                   (__attribute__((address_space(3))) void*)l,
                                   16, 0, 0);
}

// ---- kernel 1: per-row absmean quantization: Wq = bf16(round(W/scale)), scale[row] ----
__global__ __launch_bounds__(256) void quant_weight_k(const float* __restrict__ W,
                                                      unsigned short* __restrict__ Wq,
                                                      float* __restrict__ scale) {
  const int row = blockIdx.x;
  const int t   = threadIdx.x;
  const float4* wr = reinterpret_cast<const float4*>(W + (size_t)row * KIN);
  float4 v[4];
  double s = 0.0;
#pragma unroll
  for (int i = 0; i < 4; ++i) {
    v[i] = wr[t + i * 256];
    s += fabs((double)v[i].x) + fabs((double)v[i].y) +
         fabs((double)v[i].z) + fabs((double)v[i].w);
  }
#pragma unroll
  for (int off = 32; off > 0; off >>= 1) s += __shfl_down(s, off);
  __shared__ double red[4];
  if ((t & 63) == 0) red[t >> 6] = s;
  __syncthreads();
  const float sc = (float)((red[0] + red[1] + red[2] + red[3]) * (1.0 / KIN));
  if (t == 0) scale[row] = sc;
  ushort4* qr = reinterpret_cast<ushort4*>(Wq + (size_t)row * KIN);
#pragma unroll
  for (int i = 0; i < 4; ++i) {
    ushort4 q;
    q.x = f32_to_bf16(rintf(v[i].x / sc));
    q.y = f32_to_bf16(rintf(v[i].y / sc));
    q.z = f32_to_bf16(rintf(v[i].z / sc));
    q.w = f32_to_bf16(rintf(v[i].w / sc));
    qr[t + i * 256] = q;
  }
}

// ---- kernel 2: input fp32 -> bf16 ----
__global__ __launch_bounds__(256) void conv_input_k(const float* __restrict__ X,
                                                    unsigned short* __restrict__ Xb) {
  const int i = blockIdx.x * 256 + threadIdx.x;
  float4 v = reinterpret_cast<const float4*>(X)[i];
  ushort4 q;
  q.x = f32_to_bf16(v.x); q.y = f32_to_bf16(v.y);
  q.z = f32_to_bf16(v.z); q.w = f32_to_bf16(v.w);
  reinterpret_cast<ushort4*>(Xb)[i] = q;
}

// ---- kernel 3: 256x256x64 8-phase pipelined GEMM (T1+T2+T3+T4+T5) ----
// C[t,o] = scale[o]*(Xb[t,:].Wq[o,:]) + bias[o].  Both operands row-major [row][K].
//
// LDS map (128 KiB): A: [buf][256 rows][64 bf16] at 0 + buf*32768
//                    B: same at 65536 + buf*32768
// st-swizzle: LDS linear (row, c) holds global (row, c ^ ((row&7)<<4)); applied by
// pre-swizzling the global source lane address (global_load_lds dest must be linear)
// and XOR-ing the same pattern into every ds_read address.
//
// Schedule per K-tile t (buf = t&1), 4 phases:
//  ph0: ds_read A m0-3 (8) + B n0-1 (4); stage A(t+1)h0 -> buf^1 ; MFMA m0-3 x n0-1
//  ph1: ds_read B n2-3 (4);              stage A(t+1)h1 -> buf^1 ; MFMA m0-3 x n2-3
//  ph2: ds_read A m4-7 (8);              stage B(t+2)h0 -> buf   ; MFMA m4-7 x n2-3
//  ph3: (no reads);                      stage B(t+2)h1 -> buf   ; MFMA m4-7 x n0-1
//       then s_waitcnt vmcnt(4) (counted, never 0 until last 2 tiles) + barrier.
// Slot-overwrite safety: every slot's last ds_read completes (lgkmcnt(0)) at least
// one barrier-pair before its overwriting stage issues; sched_barrier(0) at each
// phase top pins instructions to their phase.
__global__ __launch_bounds__(512, 2) void gemm_k(const unsigned short* __restrict__ Xb,
                                                 const unsigned short* __restrict__ Wq,
                                                 const float* __restrict__ scale,
                                                 const float* __restrict__ bias,
                                                 float* __restrict__ out) {
  __shared__ alignas(16) char lds[131072];

  // T1: XCD-aware swizzle (1376 % 8 == 0 -> bijective)
  int bid = (int)blockIdx.x;
  bid = (bid & 7) * (NWG / 8) + (bid >> 3);
  const int trow = bid / NTCOL;
  const int tcol = bid % NTCOL;

  const int tid  = (int)threadIdx.x;
  const int lane = tid & 63;
  const int wave = tid >> 6;   // 0..7
  const int wm   = wave >> 2;  // 0..1 : M half (128 rows)
  const int wn   = wave & 3;   // 0..3 : N quarter (64 cols)

  // ---- staging lane addresses (inverse-swizzled global source, linear LDS dest) ----
  const int l8 = lane >> 3;                          // 0..7 -> row within 8-row group
  const size_t rowb = (size_t)KIN * 2;               // 8192 B per row
  const int swzl = ((lane & 7) ^ l8) * 16;           // pre-swizzled k-byte within 128B slice
  const char* gA = (const char*)Xb + (size_t)(trow * BM + wave * 16 + l8) * rowb + swzl;
  const char* gB = (const char*)Wq + (size_t)(tcol * BN + wave * 16 + l8) * rowb + swzl;
  char* lA = lds + wave * 2048;            // + buf*32768 + h*16384 (+1024 for 2nd load)
  char* lB = lds + 65536 + wave * 2048;

#define STAGE(gp, lp, koff) do {                                             \
    gload_lds16((gp) + (koff), (lp));                                        \
    gload_lds16((gp) + (koff) + (size_t)65536, (char*)(lp) + 1024);          \
  } while (0)

  // ---- ds_read bases (swizzled) ----
  const int lr = lane & 15;
  const int hi = lane >> 4;
  const int swz0 = (hi * 16) ^ ((lr & 7) << 4);
  const int swz[2] = { swz0, swz0 ^ 64 };            // kk=0 / kk=1 (XOR, not add: bit6 overlaps)
  const char* rdA = lds + wm * 16384 + lr * 128;
  const char* rdB = lds + 65536 + (wn >> 1) * 16384 + ((wn & 1) * 64 + lr) * 128;

  f32x4 acc[8][4];
#pragma unroll
  for (int m = 0; m < 8; ++m)
#pragma unroll
    for (int n = 0; n < 4; ++n) acc[m][n] = (f32x4){0.f, 0.f, 0.f, 0.f};
  bf16x8 afr[4][2], bfr[4][2];

#define LDA(mf, mbase, kk) afr[mf][kk] = *(const bf16x8*)(rdA + cur + ((mbase) + (mf)) * 2048 + swz[kk])
#define LDB(nf, kk)        bfr[nf][kk] = *(const bf16x8*)(rdB + cur + (nf) * 2048 + swz[kk])

#define QUAD(MB, NB)                                                          \
    _Pragma("unroll") for (int mf = 0; mf < 4; ++mf)                          \
    _Pragma("unroll") for (int nf = 0; nf < 2; ++nf)                          \
    _Pragma("unroll") for (int kk = 0; kk < 2; ++kk)                          \
      acc[(MB) + mf][(NB) + nf] = __builtin_amdgcn_mfma_f32_16x16x32_bf16(    \
          afr[mf][kk], bfr[(NB) + nf][kk], acc[(MB) + mf][(NB) + nf], 0, 0, 0)

#define PHASE_MID()                                         \
    __builtin_amdgcn_s_barrier();                           \
    asm volatile("s_waitcnt lgkmcnt(0)" ::: "memory");      \
    __builtin_amdgcn_sched_barrier(0);                      \
    __builtin_amdgcn_s_setprio(1)

#define PHASE_END()                                         \
    __builtin_amdgcn_s_setprio(0);                          \
    __builtin_amdgcn_s_barrier()

  // ---- prologue: tile0 (A,B) + tile1 (B); tile1's A is staged by loop t=0 ----
  STAGE(gA,              lA,                 0);    // A(0) h0
  STAGE(gA + 128 * rowb, lA + 16384,         0);    // A(0) h1
  STAGE(gB,              lB,                 0);    // B(0) h0
  STAGE(gB + 128 * rowb, lB + 16384,         0);    // B(0) h1
  STAGE(gB,              lB + 32768,         128);  // B(1) h0
  STAGE(gB + 128 * rowb, lB + 32768 + 16384, 128);  // B(1) h1
  asm volatile("s_waitcnt vmcnt(4)" ::: "memory");  // tile0's 8 loads done; B(1) in flight
  __builtin_amdgcn_s_barrier();

#pragma unroll 2
  for (int t = 0; t < NT; ++t) {
    const int cur = (t & 1) * 32768;
    const int nxt = cur ^ 32768;
    const size_t kA = (size_t)(t + 1) * 128;
    const size_t kB = (size_t)(t + 2) * 128;

    // ---------- phase 0 ----------
    __builtin_amdgcn_sched_barrier(0);
#pragma unroll
    for (int mf = 0; mf < 4; ++mf) { LDA(mf, 0, 0); LDA(mf, 0, 1); }
#pragma unroll
    for (int nf = 0; nf < 2; ++nf) { LDB(nf, 0); LDB(nf, 1); }
    if (t + 1 < NT) STAGE(gA, lA + nxt, kA);                      // A(t+1) h0
    PHASE_MID();
    QUAD(0, 0);
    PHASE_END();

    // ---------- phase 1 ----------
    __builtin_amdgcn_sched_barrier(0);
#pragma unroll
    for (int nf = 2; nf < 4; ++nf) { LDB(nf, 0); LDB(nf, 1); }
    if (t + 1 < NT) STAGE(gA + 128 * rowb, lA + nxt + 16384, kA); // A(t+1) h1
    PHASE_MID();
    QUAD(0, 2);
    PHASE_END();

    // ---------- phase 2 ----------
    __builtin_amdgcn_sched_barrier(0);
#pragma unroll
    for (int mf = 0; mf < 4; ++mf) { LDA(mf, 4, 0); LDA(mf, 4, 1); }
    if (t + 2 < NT) STAGE(gB, lB + cur, kB);                      // B(t+2) h0 (same-parity buf)
    PHASE_MID();
    QUAD(4, 2);
    PHASE_END();

    // ---------- phase 3 ----------
    __builtin_amdgcn_sched_barrier(0);
    if (t + 2 < NT) STAGE(gB + 128 * rowb, lB + cur + 16384, kB); // B(t+2) h1
    PHASE_MID();
    QUAD(4, 0);
    __builtin_amdgcn_s_setprio(0);
    if (t < NT - 2) { asm volatile("s_waitcnt vmcnt(4)" ::: "memory"); }  // counted, never 0
    else           { asm volatile("s_waitcnt vmcnt(0)" ::: "memory"); }  // epilogue drain
    __builtin_amdgcn_s_barrier();
  }

  // ---- epilogue: C/D layout col = lane&15, row = (lane>>4)*4 + reg ----
  const int gr_base = trow * BM + wm * 128 + hi * 4;
  const int gc_base = tcol * BN + wn * 64 + lr;
#pragma unroll
  for (int nf = 0; nf < 4; ++nf) {
    const int gc = gc_base + nf * 16;
    const float s  = scale[gc];
    const float bb = bias[gc];
#pragma unroll
    for (int mf = 0; mf < 8; ++mf) {
      const size_t rb = (size_t)(gr_base + mf * 16) * NOUT + gc;
#pragma unroll
      for (int j = 0; j < 4; ++j)
        out[rb + (size_t)j * NOUT] = acc[mf][nf][j] * s + bb;
    }
  }
#undef STAGE
#undef LDA
#undef LDB
#undef QUAD
#undef PHASE_MID
#undef PHASE_END
}

extern "C" void kernel_launch(void* const* d_in, const int* in_sizes, int n_in,
                              void* d_out, int out_size, void* d_ws, size_t ws_size,
                              hipStream_t stream) {
  const float* X  = (const float*)d_in[0];   // [8192, 4096] fp32
  const float* W  = (const float*)d_in[1];   // [11008, 4096] fp32
  const float* Bi = (const float*)d_in[2];   // [11008] fp32
  float* out = (float*)d_out;                // [8192, 11008] fp32

  const size_t xb_bytes = (size_t)TOKENS * KIN * 2;  // 64 MiB
  const size_t wq_bytes = (size_t)NOUT * KIN * 2;    // 86 MiB
  const size_t need = xb_bytes + wq_bytes + (size_t)NOUT * sizeof(float);
  if (ws_size < need) return;  // needs ~157.3 MB scratch

  char* ws = (char*)d_ws;
  unsigned short* Xb = (unsigned short*)ws;
  unsigned short* Wq = (unsigned short*)(ws + xb_bytes);
  float* scale = (float*)(ws + xb_bytes + wq_bytes);

  quant_weight_k<<<NOUT, 256, 0, stream>>>(W, Wq, scale);
  conv_input_k<<<(TOKENS * KIN / 4) / 256, 256, 0, stream>>>(X, Xb);
  gemm_k<<<NWG, 512, 0, stream>>>(Xb, Wq, scale, Bi, out);
}